// Round 11
// baseline (53.024 us; speedup 1.0000x reference)
//
#include <hip/hip_runtime.h>
#include <math.h>
#include <stdint.h>

// Router: x (4,8192,1024) f32, W (64,1024) f32
// out = [ top_idx (32768,2) as float | top_gates (32768,2) | loss (1) ]
// ws  = 64 floats of per-expert prob sums (atomic accumulated)
//
// R11 = R10 (MFMA, exact 3-way bf16 split, 6 passes) + 2 blocks/CU.
// R10 measured: 12% MfmaUtil / 14% VALU / DS ~22us pipe => ~25us exposed
// latency at 1 block/CU (112KB LDS, every tile barrier drains alone).
// R11: BM=64, grid=512, LDS=80KB exactly -> 2 blocks/CU (16 waves).
// K split across wave halves: wave w = (mt=w&3, kh=w>>2) does 16 tokens x
// 64 experts x its K32 half per BK64 tile; halves combined in LDS epilogue.

constexpr int DMODEL = 1024;
constexpr int NEXP   = 64;
constexpr int BM     = 64;    // tokens per block
constexpr int BK     = 64;    // K per tile
constexpr int NTOK   = 32768;
constexpr int NTILE  = DMODEL / BK;  // 16

// LDS map (bytes), total 81920 (80 KB):
//   XS @ 0     : fp32 x tile [2][64][64], chunk-swizzled       (32768)
//   WS @ 32768 : bf16 W split [2][3 comp][64 e][64 k], swizzled (49152)
// epilogue overlay @0: logits [64][68 f32] (17408), maxArr@18432,
//   invArr@18688, psum[8][64]@18944
constexpr int XS   = 0;
constexpr int XSB  = 64 * 64 * 4;           // 16384 per buffer
constexpr int WS   = 32768;
constexpr int WSB  = 3 * 64 * 64 * 2;       // 24576 per buffer
constexpr int WCMP = 64 * 64 * 2;           // 8192 per component
constexpr int LSTR = 68 * 4;                // logits row stride (bytes)

typedef __attribute__((ext_vector_type(8))) short short8;
typedef __attribute__((ext_vector_type(4))) float f32x4;

__device__ __forceinline__ void gload16(const float* g, char* l) {
    __builtin_amdgcn_global_load_lds(
        (const __attribute__((address_space(1))) unsigned int*)g,
        (__attribute__((address_space(3))) unsigned int*)l,
        16, 0, 0);
}

// split one fp32 into 3 bf16 (truncation chunks; x = h+m+l exact to 2^-24)
__device__ __forceinline__ void split3(float x, short& h, short& m, short& l) {
    uint32_t u  = __float_as_uint(x);
    uint32_t uh = u & 0xffff0000u;
    float    r  = x - __uint_as_float(uh);
    uint32_t ur = __float_as_uint(r);
    uint32_t um = ur & 0xffff0000u;
    float    r2 = r - __uint_as_float(um);
    h = (short)(uh >> 16);
    m = (short)(um >> 16);
    l = (short)(__float_as_uint(r2) >> 16);
}

__global__ __launch_bounds__(512, 2) void router_kernel(
    const float* __restrict__ x, const float* __restrict__ W,
    float* __restrict__ out, float* __restrict__ expert_sums)
{
    __shared__ __align__(16) char smem[81920];

    const int tid  = threadIdx.x;
    const int lane = tid & 63;
    const int w    = tid >> 6;           // wave id 0..7
    const int mt   = w & 3;              // M-tile (16 tokens each)
    const int kh   = w >> 2;             // K-half of each BK64 tile
    const int tok0 = blockIdx.x * BM;

    f32x4 acc[4];
#pragma unroll
    for (int nt = 0; nt < 4; ++nt) acc[nt] = (f32x4){0.f, 0.f, 0.f, 0.f};

    // ---- x staging: wave w stages rows [w*8, w*8+8) ----
    // phys 16B-chunk c of row r holds logical chunk c ^ (r&15)
    auto stageX = [&](int buf, int tile) {
#pragma unroll
        for (int i = 0; i < 2; ++i) {
            const int r0 = w * 8 + i * 4;
            const int r  = r0 + (lane >> 4);
            const int c  = lane & 15;
            const float* src = x + (size_t)(tok0 + r) * DMODEL + tile * BK
                                 + ((c ^ (r & 15)) << 2);
            gload16(src, smem + XS + buf * XSB + r0 * 256 + (lane << 4));
        }
    };

    // ---- W slice -> 3x bf16 LDS ----
    // thread t owns expert we = t>>3, 8-float chunk wc = t&7 of the k-tile
    const int we  = tid >> 3;
    const int wc  = tid & 7;
    const int wph = wc ^ (we & 7);       // chunk swizzle (read side inverts)
    const float* wgp = W + (size_t)we * DMODEL + wc * 8;

    auto convW = [&](int buf, float4 a, float4 b) {
        short8 sH, sM, sL;
        float v[8] = {a.x, a.y, a.z, a.w, b.x, b.y, b.z, b.w};
#pragma unroll
        for (int j = 0; j < 8; ++j) {
            short h, m, l; split3(v[j], h, m, l);
            sH[j] = h; sM[j] = m; sL[j] = l;
        }
        char* d = smem + WS + buf * WSB + we * 128 + wph * 16;
        *reinterpret_cast<short8*>(d)             = sH;
        *reinterpret_cast<short8*>(d + WCMP)      = sM;
        *reinterpret_cast<short8*>(d + 2 * WCMP)  = sL;
    };

    // prologue: tile 0
    stageX(0, 0);
    {
        float4 a = *reinterpret_cast<const float4*>(wgp);
        float4 b = *reinterpret_cast<const float4*>(wgp + 4);
        convW(0, a, b);
    }
    __syncthreads();

    int buf = 0;
    for (int tile = 0; tile < NTILE; ++tile) {
        float4 wa, wb;
        if (tile + 1 < NTILE) {
            stageX(buf ^ 1, tile + 1);
            wa = *reinterpret_cast<const float4*>(wgp + (tile + 1) * BK);
            wb = *reinterpret_cast<const float4*>(wgp + (tile + 1) * BK + 4);
        }

        // this wave's K32 half: ks = kh
        {
            const int ks = kh;
            const int rl = mt * 16 + (lane & 15);
            const int c0 = ks * 8 + (lane >> 4) * 2;
            const char* xrow = smem + XS + buf * XSB + rl * 256;
            const float4 xa = *reinterpret_cast<const float4*>(
                xrow + ((c0 ^ (lane & 15)) << 4));
            const float4 xb = *reinterpret_cast<const float4*>(
                xrow + (((c0 + 1) ^ (lane & 15)) << 4));
            short8 aH, aM, aL;
            {
                float v[8] = {xa.x, xa.y, xa.z, xa.w, xb.x, xb.y, xb.z, xb.w};
#pragma unroll
                for (int j = 0; j < 8; ++j) {
                    short h, m, l; split3(v[j], h, m, l);
                    aH[j] = h; aM[j] = m; aL[j] = l;
                }
            }
#pragma unroll
            for (int nt = 0; nt < 4; ++nt) {
                const int ef = nt * 16 + (lane & 15);
                const int q  = ks * 4 + (lane >> 4);
                const char* wrow = smem + WS + buf * WSB + ef * 128
                                 + ((q ^ (ef & 7)) << 4);
                const short8 bH = *reinterpret_cast<const short8*>(wrow);
                const short8 bM = *reinterpret_cast<const short8*>(wrow + WCMP);
                const short8 bL = *reinterpret_cast<const short8*>(wrow + 2 * WCMP);
                acc[nt] = __builtin_amdgcn_mfma_f32_16x16x32_bf16(aH, bH, acc[nt], 0, 0, 0);
                acc[nt] = __builtin_amdgcn_mfma_f32_16x16x32_bf16(aH, bM, acc[nt], 0, 0, 0);
                acc[nt] = __builtin_amdgcn_mfma_f32_16x16x32_bf16(aM, bH, acc[nt], 0, 0, 0);
                acc[nt] = __builtin_amdgcn_mfma_f32_16x16x32_bf16(aH, bL, acc[nt], 0, 0, 0);
                acc[nt] = __builtin_amdgcn_mfma_f32_16x16x32_bf16(aM, bM, acc[nt], 0, 0, 0);
                acc[nt] = __builtin_amdgcn_mfma_f32_16x16x32_bf16(aL, bH, acc[nt], 0, 0, 0);
            }
        }

        if (tile + 1 < NTILE) convW(buf ^ 1, wa, wb);
        __syncthreads();
        buf ^= 1;
    }

    // ---- combine K-halves into LDS logits [64 tok][68 f32 stride] ----
    // C/D layout: col(lane&15)=expert frag idx, row=(lane>>4)*4+r (verified R10)
    if (kh == 0) {
#pragma unroll
        for (int nt = 0; nt < 4; ++nt)
#pragma unroll
            for (int r = 0; r < 4; ++r) {
                const int t = mt * 16 + (lane >> 4) * 4 + r;
                const int e = nt * 16 + (lane & 15);
                *reinterpret_cast<float*>(smem + t * LSTR + e * 4) = acc[nt][r];
            }
    }
    __syncthreads();
    if (kh == 1) {
#pragma unroll
        for (int nt = 0; nt < 4; ++nt)
#pragma unroll
            for (int r = 0; r < 4; ++r) {
                const int t = mt * 16 + (lane >> 4) * 4 + r;
                const int e = nt * 16 + (lane & 15);
                float* p = reinterpret_cast<float*>(smem + t * LSTR + e * 4);
                *p += acc[nt][r];
            }
    }
    __syncthreads();

    float* maxArr = reinterpret_cast<float*>(smem + 18432);
    float* invArr = reinterpret_cast<float*>(smem + 18688);
    float* psum   = reinterpret_cast<float*>(smem + 18944);

    // pass 1: per-token max, softmax denom, top-2, outputs (threads 0..63)
    if (tid < BM) {
        const char* lrow = smem + tid * LSTR;
        float4 L[16];
#pragma unroll
        for (int i = 0; i < 16; ++i)
            L[i] = *reinterpret_cast<const float4*>(lrow + i * 16);

        float mx = -INFINITY;
#pragma unroll
        for (int i = 0; i < 16; ++i)
            mx = fmaxf(mx, fmaxf(fmaxf(L[i].x, L[i].y), fmaxf(L[i].z, L[i].w)));

        float v0 = -INFINITY, v1 = -INFINITY;
        int   i0 = NEXP, i1 = NEXP;
        float s = 0.f;
#pragma unroll
        for (int i = 0; i < 16; ++i) {
            const float vv[4] = {L[i].x, L[i].y, L[i].z, L[i].w};
#pragma unroll
            for (int c = 0; c < 4; ++c) {
                const float v = vv[c];
                const int  gi = i * 4 + c;
                s += __expf(v - mx);
                if (v > v0) { v1 = v0; i1 = i0; v0 = v; i0 = gi; }
                else if (v > v1) { v1 = v; i1 = gi; }
            }
        }
        maxArr[tid] = mx;
        invArr[tid] = 1.0f / s;

        const float q = __expf(v1 - v0);
        const float d = 1.0f + q;
        const size_t tok = (size_t)tok0 + tid;
        reinterpret_cast<float2*>(out)[tok]            = make_float2((float)i0, (float)i1);
        reinterpret_cast<float2*>(out + 2 * NTOK)[tok] = make_float2(1.0f / d, q / d);
    }
    __syncthreads();

    // pass 2: per-expert prob sums (512 threads: e = tid&63, grp = tid>>6,
    // 8 tokens per group)
    {
        const int e = tid & 63, grp = tid >> 6;
        float s = 0.f;
#pragma unroll
        for (int i = 0; i < 8; ++i) {
            const int t = grp * 8 + i;
            const float lg = *reinterpret_cast<const float*>(smem + t * LSTR + e * 4);
            s += __expf(lg - maxArr[t]) * invArr[t];
        }
        psum[grp * 64 + e] = s;
    }
    __syncthreads();
    if (tid < 64) {
        float s = 0.f;
#pragma unroll
        for (int g = 0; g < 8; ++g) s += psum[g * 64 + tid];
        atomicAdd(&expert_sums[tid], s);
    }
}

__global__ void loss_kernel(const float* __restrict__ sums, float* __restrict__ out)
{
    const int lane = threadIdx.x;  // 64 threads
    float pv = sums[lane] * (1.0f / (float)NTOK);  // avg_probs[lane]
    float m = pv;
#pragma unroll
    for (int off = 32; off; off >>= 1) m += __shfl_xor(m, off, 64);
    m *= (1.0f / (float)NEXP);
    float d = pv - m;
    float v = d * d;
#pragma unroll
    for (int off = 32; off; off >>= 1) v += __shfl_xor(v, off, 64);
    v *= (1.0f / (float)(NEXP - 1));  // ddof=1
    if (lane == 0) {
        float stdv = sqrtf(v);
        float r = stdv / (m + 1e-6f);
        out[4 * NTOK] = r * r;
    }
}

extern "C" void kernel_launch(void* const* d_in, const int* in_sizes, int n_in,
                              void* d_out, int out_size, void* d_ws, size_t ws_size,
                              hipStream_t stream)
{
    const float* x = (const float*)d_in[0];
    const float* W = (const float*)d_in[1];
    float* out  = (float*)d_out;
    float* sums = (float*)d_ws;

    hipMemsetAsync(d_ws, 0, NEXP * sizeof(float), stream);

    hipLaunchKernelGGL(router_kernel, dim3(NTOK / BM), dim3(512), 0, stream,
                       x, W, out, sums);
    hipLaunchKernelGGL(loss_kernel, dim3(1), dim3(64), 0, stream, sums, out);
}

// Round 12
// 51.575 us; speedup vs baseline: 1.0281x; 1.0281x over previous
//
#include <hip/hip_runtime.h>
#include <math.h>
#include <stdint.h>

// Router: x (4,8192,1024) f32, W (64,1024) f32
// out = [ top_idx (32768,2) as float | top_gates (32768,2) | loss (1) ]
// ws  = [0,256): 64-float expert prob sums | [256, 256+384K): pre-split W bf16x3
//
// R12 = R11 (MFMA, exact 3-way bf16 split, 6 passes) with:
//  (1) W pre-split ONCE into global (wsplit_kernel) -> k-loop staging is pure
//      global_load_lds (5/thread/tile), no convW VALU / ds_writes in loop.
//  (2) counted-vmcnt double barrier per tile (T4): stage(t+1); vmcnt(5);
//      barrier; MFMA; barrier — staging loads stay in flight across barriers,
//      vmcnt drains to 0 only at the last tile.
// Fallback (ws_size too small): R11 kernel verbatim.

constexpr int DMODEL = 1024;
constexpr int NEXP   = 64;
constexpr int BM     = 64;    // tokens per block
constexpr int BK     = 64;    // K per tile
constexpr int NTOK   = 32768;
constexpr int NTILE  = DMODEL / BK;  // 16

// LDS map (bytes), total 81920 (80 KB), 2 blocks/CU:
//   XS @ 0     : fp32 x tile [2][64][64], chunk-swizzled        (32768)
//   WS @ 32768 : bf16 W split [2][3 comp][64 e][64 k], swizzled (49152)
// epilogue overlay @0: logits [64][68 f32], maxArr@18432, invArr@18688,
//   psum[8][64]@18944
constexpr int XS   = 0;
constexpr int XSB  = 64 * 64 * 4;           // 16384 per buffer
constexpr int WS   = 32768;
constexpr int WSB  = 3 * 64 * 64 * 2;       // 24576 per buffer
constexpr int WCMP = 64 * 64 * 2;           // 8192 per component
constexpr int LSTR = 68 * 4;                // logits row stride (bytes)

constexpr size_t WSPLIT_OFF   = 256;
constexpr size_t WSPLIT_BYTES = (size_t)NTILE * WSB;   // 393216

typedef __attribute__((ext_vector_type(8))) short short8;
typedef __attribute__((ext_vector_type(4))) float f32x4;

__device__ __forceinline__ void gload16(const void* g, void* l) {
    __builtin_amdgcn_global_load_lds(
        (const __attribute__((address_space(1))) unsigned int*)g,
        (__attribute__((address_space(3))) unsigned int*)l,
        16, 0, 0);
}

// split one fp32 into 3 bf16 (truncation chunks; x = h+m+l exact to 2^-24)
__device__ __forceinline__ void split3(float x, short& h, short& m, short& l) {
    uint32_t u  = __float_as_uint(x);
    uint32_t uh = u & 0xffff0000u;
    float    r  = x - __uint_as_float(uh);
    uint32_t ur = __float_as_uint(r);
    uint32_t um = ur & 0xffff0000u;
    float    r2 = r - __uint_as_float(um);
    h = (short)(uh >> 16);
    m = (short)(um >> 16);
    l = (short)(__float_as_uint(r2) >> 16);
}

// ---- one-shot W pre-split: 8192 threads, thread g = (expert e, 8-chunk c) ----
__global__ void wsplit_kernel(const float* __restrict__ W, char* __restrict__ dst)
{
    const int g = blockIdx.x * 256 + threadIdx.x;   // 0..8191
    const int e = g >> 7;        // expert 0..63
    const int c = g & 127;       // 8-float chunk within the 1024-k row
    const int tile = c >> 3;
    const int q    = c & 7;
    const float* src = W + (size_t)e * DMODEL + c * 8;
    const float4 a = *reinterpret_cast<const float4*>(src);
    const float4 b = *reinterpret_cast<const float4*>(src + 4);
    short8 sH, sM, sL;
    const float v[8] = {a.x, a.y, a.z, a.w, b.x, b.y, b.z, b.w};
#pragma unroll
    for (int j = 0; j < 8; ++j) {
        short h, m, l; split3(v[j], h, m, l);
        sH[j] = h; sM[j] = m; sL[j] = l;
    }
    char* base = dst + (size_t)tile * WSB + e * 128 + ((q ^ (e & 7)) << 4);
    *reinterpret_cast<short8*>(base)            = sH;
    *reinterpret_cast<short8*>(base + WCMP)     = sM;
    *reinterpret_cast<short8*>(base + 2 * WCMP) = sL;
}

__global__ __launch_bounds__(512, 2) void router_kernel(
    const float* __restrict__ x, const char* __restrict__ wsAll,
    float* __restrict__ out, float* __restrict__ expert_sums)
{
    __shared__ __align__(16) char smem[81920];

    const int tid  = threadIdx.x;
    const int lane = tid & 63;
    const int w    = tid >> 6;           // wave id 0..7
    const int mt   = w & 3;              // M-tile (16 tokens each)
    const int kh   = w >> 2;             // K-half of each BK64 tile
    const int tok0 = blockIdx.x * BM;

    f32x4 acc[4];
#pragma unroll
    for (int nt = 0; nt < 4; ++nt) acc[nt] = (f32x4){0.f, 0.f, 0.f, 0.f};

    // ---- x staging: wave w stages rows [w*8, w*8+8); 2 instrs ----
    auto stageX = [&](int buf, int tile) {
#pragma unroll
        for (int i = 0; i < 2; ++i) {
            const int r0 = w * 8 + i * 4;
            const int r  = r0 + (lane >> 4);
            const int c  = lane & 15;
            const float* src = x + (size_t)(tok0 + r) * DMODEL + tile * BK
                                 + ((c ^ (r & 15)) << 2);
            gload16(src, smem + XS + buf * XSB + r0 * 256 + (lane << 4));
        }
    };
    // ---- W staging: pre-split bf16x3, linear copy; 3 instrs ----
    auto stageW = [&](int buf, int tile) {
        const char* src = wsAll + (size_t)tile * WSB + w * 1024 + (lane << 4);
        char* dst = smem + WS + buf * WSB + w * 1024 + (lane << 4);
#pragma unroll
        for (int j = 0; j < 3; ++j)
            gload16(src + j * WCMP, dst + j * WCMP);
    };

    // prologue: tile 0 (5 loads in flight)
    stageX(0, 0);
    stageW(0, 0);

    int buf = 0;
    for (int tile = 0; tile < NTILE; ++tile) {
        if (tile + 1 < NTILE) {
            stageX(buf ^ 1, tile + 1);
            stageW(buf ^ 1, tile + 1);
            asm volatile("s_waitcnt vmcnt(5)" ::: "memory");  // tile's 5 landed
        } else {
            asm volatile("s_waitcnt vmcnt(0)" ::: "memory");
        }
        __builtin_amdgcn_sched_barrier(0);
        __builtin_amdgcn_s_barrier();            // (a) buf ready block-wide

        // this wave's K32 half: ks = kh
        {
            const int ks = kh;
            const int rl = mt * 16 + (lane & 15);
            const int c0 = ks * 8 + (lane >> 4) * 2;
            const char* xrow = smem + XS + buf * XSB + rl * 256;
            const float4 xa = *reinterpret_cast<const float4*>(
                xrow + ((c0 ^ (lane & 15)) << 4));
            const float4 xb = *reinterpret_cast<const float4*>(
                xrow + (((c0 + 1) ^ (lane & 15)) << 4));
            short8 aH, aM, aL;
            {
                float v[8] = {xa.x, xa.y, xa.z, xa.w, xb.x, xb.y, xb.z, xb.w};
#pragma unroll
                for (int j = 0; j < 8; ++j) {
                    short h, m, l; split3(v[j], h, m, l);
                    aH[j] = h; aM[j] = m; aL[j] = l;
                }
            }
#pragma unroll
            for (int nt = 0; nt < 4; ++nt) {
                const int ef = nt * 16 + (lane & 15);
                const int q  = ks * 4 + (lane >> 4);
                const char* wrow = smem + WS + buf * WSB + ef * 128
                                 + ((q ^ (ef & 7)) << 4);
                const short8 bH = *reinterpret_cast<const short8*>(wrow);
                const short8 bM = *reinterpret_cast<const short8*>(wrow + WCMP);
                const short8 bL = *reinterpret_cast<const short8*>(wrow + 2 * WCMP);
                acc[nt] = __builtin_amdgcn_mfma_f32_16x16x32_bf16(aH, bH, acc[nt], 0, 0, 0);
                acc[nt] = __builtin_amdgcn_mfma_f32_16x16x32_bf16(aH, bM, acc[nt], 0, 0, 0);
                acc[nt] = __builtin_amdgcn_mfma_f32_16x16x32_bf16(aM, bH, acc[nt], 0, 0, 0);
                acc[nt] = __builtin_amdgcn_mfma_f32_16x16x32_bf16(aH, bL, acc[nt], 0, 0, 0);
                acc[nt] = __builtin_amdgcn_mfma_f32_16x16x32_bf16(aM, bM, acc[nt], 0, 0, 0);
                acc[nt] = __builtin_amdgcn_mfma_f32_16x16x32_bf16(aL, bH, acc[nt], 0, 0, 0);
            }
        }
        __builtin_amdgcn_s_barrier();            // (b) all done reading buf
        buf ^= 1;
    }

    // ---- combine K-halves into LDS logits [64 tok][68 f32 stride] ----
    // C/D layout: col(lane&15)=expert frag idx, row=(lane>>4)*4+r (verified R10)
    if (kh == 0) {
#pragma unroll
        for (int nt = 0; nt < 4; ++nt)
#pragma unroll
            for (int r = 0; r < 4; ++r) {
                const int t = mt * 16 + (lane >> 4) * 4 + r;
                const int e = nt * 16 + (lane & 15);
                *reinterpret_cast<float*>(smem + t * LSTR + e * 4) = acc[nt][r];
            }
    }
    __syncthreads();
    if (kh == 1) {
#pragma unroll
        for (int nt = 0; nt < 4; ++nt)
#pragma unroll
            for (int r = 0; r < 4; ++r) {
                const int t = mt * 16 + (lane >> 4) * 4 + r;
                const int e = nt * 16 + (lane & 15);
                float* p = reinterpret_cast<float*>(smem + t * LSTR + e * 4);
                *p += acc[nt][r];
            }
    }
    __syncthreads();

    float* maxArr = reinterpret_cast<float*>(smem + 18432);
    float* invArr = reinterpret_cast<float*>(smem + 18688);
    float* psum   = reinterpret_cast<float*>(smem + 18944);

    // pass 1: per-token max, softmax denom, top-2, outputs (threads 0..63)
    if (tid < BM) {
        const char* lrow = smem + tid * LSTR;
        float4 L[16];
#pragma unroll
        for (int i = 0; i < 16; ++i)
            L[i] = *reinterpret_cast<const float4*>(lrow + i * 16);

        float mx = -INFINITY;
#pragma unroll
        for (int i = 0; i < 16; ++i)
            mx = fmaxf(mx, fmaxf(fmaxf(L[i].x, L[i].y), fmaxf(L[i].z, L[i].w)));

        float v0 = -INFINITY, v1 = -INFINITY;
        int   i0 = NEXP, i1 = NEXP;
        float s = 0.f;
#pragma unroll
        for (int i = 0; i < 16; ++i) {
            const float vv[4] = {L[i].x, L[i].y, L[i].z, L[i].w};
#pragma unroll
            for (int c = 0; c < 4; ++c) {
                const float v = vv[c];
                const int  gi = i * 4 + c;
                s += __expf(v - mx);
                if (v > v0) { v1 = v0; i1 = i0; v0 = v; i0 = gi; }
                else if (v > v1) { v1 = v; i1 = gi; }
            }
        }
        maxArr[tid] = mx;
        invArr[tid] = 1.0f / s;

        const float q = __expf(v1 - v0);
        const float d = 1.0f + q;
        const size_t tok = (size_t)tok0 + tid;
        reinterpret_cast<float2*>(out)[tok]            = make_float2((float)i0, (float)i1);
        reinterpret_cast<float2*>(out + 2 * NTOK)[tok] = make_float2(1.0f / d, q / d);
    }
    __syncthreads();

    // pass 2: per-expert prob sums (512 threads: e = tid&63, grp = tid>>6)
    {
        const int e = tid & 63, grp = tid >> 6;
        float s = 0.f;
#pragma unroll
        for (int i = 0; i < 8; ++i) {
            const int t = grp * 8 + i;
            const float lg = *reinterpret_cast<const float*>(smem + t * LSTR + e * 4);
            s += __expf(lg - maxArr[t]) * invArr[t];
        }
        psum[grp * 64 + e] = s;
    }
    __syncthreads();
    if (tid < 64) {
        float s = 0.f;
#pragma unroll
        for (int g = 0; g < 8; ++g) s += psum[g * 64 + tid];
        atomicAdd(&expert_sums[tid], s);
    }
}

// ================= fallback: R11 kernel verbatim (ws too small) =============
__global__ __launch_bounds__(512, 2) void router_fallback(
    const float* __restrict__ x, const float* __restrict__ W,
    float* __restrict__ out, float* __restrict__ expert_sums)
{
    __shared__ __align__(16) char smem[81920];

    const int tid  = threadIdx.x;
    const int lane = tid & 63;
    const int w    = tid >> 6;
    const int mt   = w & 3;
    const int kh   = w >> 2;
    const int tok0 = blockIdx.x * BM;

    f32x4 acc[4];
#pragma unroll
    for (int nt = 0; nt < 4; ++nt) acc[nt] = (f32x4){0.f, 0.f, 0.f, 0.f};

    auto stageX = [&](int buf, int tile) {
#pragma unroll
        for (int i = 0; i < 2; ++i) {
            const int r0 = w * 8 + i * 4;
            const int r  = r0 + (lane >> 4);
            const int c  = lane & 15;
            const float* src = x + (size_t)(tok0 + r) * DMODEL + tile * BK
                                 + ((c ^ (r & 15)) << 2);
            gload16(src, smem + XS + buf * XSB + r0 * 256 + (lane << 4));
        }
    };

    const int we  = tid >> 3;
    const int wc  = tid & 7;
    const int wph = wc ^ (we & 7);
    const float* wgp = W + (size_t)we * DMODEL + wc * 8;

    auto convW = [&](int buf, float4 a, float4 b) {
        short8 sH, sM, sL;
        float v[8] = {a.x, a.y, a.z, a.w, b.x, b.y, b.z, b.w};
#pragma unroll
        for (int j = 0; j < 8; ++j) {
            short h, m, l; split3(v[j], h, m, l);
            sH[j] = h; sM[j] = m; sL[j] = l;
        }
        char* d = smem + WS + buf * WSB + we * 128 + wph * 16;
        *reinterpret_cast<short8*>(d)             = sH;
        *reinterpret_cast<short8*>(d + WCMP)      = sM;
        *reinterpret_cast<short8*>(d + 2 * WCMP)  = sL;
    };

    stageX(0, 0);
    {
        float4 a = *reinterpret_cast<const float4*>(wgp);
        float4 b = *reinterpret_cast<const float4*>(wgp + 4);
        convW(0, a, b);
    }
    __syncthreads();

    int buf = 0;
    for (int tile = 0; tile < NTILE; ++tile) {
        float4 wa, wb;
        if (tile + 1 < NTILE) {
            stageX(buf ^ 1, tile + 1);
            wa = *reinterpret_cast<const float4*>(wgp + (tile + 1) * BK);
            wb = *reinterpret_cast<const float4*>(wgp + (tile + 1) * BK + 4);
        }
        {
            const int ks = kh;
            const int rl = mt * 16 + (lane & 15);
            const int c0 = ks * 8 + (lane >> 4) * 2;
            const char* xrow = smem + XS + buf * XSB + rl * 256;
            const float4 xa = *reinterpret_cast<const float4*>(
                xrow + ((c0 ^ (lane & 15)) << 4));
            const float4 xb = *reinterpret_cast<const float4*>(
                xrow + (((c0 + 1) ^ (lane & 15)) << 4));
            short8 aH, aM, aL;
            {
                float v[8] = {xa.x, xa.y, xa.z, xa.w, xb.x, xb.y, xb.z, xb.w};
#pragma unroll
                for (int j = 0; j < 8; ++j) {
                    short h, m, l; split3(v[j], h, m, l);
                    aH[j] = h; aM[j] = m; aL[j] = l;
                }
            }
#pragma unroll
            for (int nt = 0; nt < 4; ++nt) {
                const int ef = nt * 16 + (lane & 15);
                const int q  = ks * 4 + (lane >> 4);
                const char* wrow = smem + WS + buf * WSB + ef * 128
                                 + ((q ^ (ef & 7)) << 4);
                const short8 bH = *reinterpret_cast<const short8*>(wrow);
                const short8 bM = *reinterpret_cast<const short8*>(wrow + WCMP);
                const short8 bL = *reinterpret_cast<const short8*>(wrow + 2 * WCMP);
                acc[nt] = __builtin_amdgcn_mfma_f32_16x16x32_bf16(aH, bH, acc[nt], 0, 0, 0);
                acc[nt] = __builtin_amdgcn_mfma_f32_16x16x32_bf16(aH, bM, acc[nt], 0, 0, 0);
                acc[nt] = __builtin_amdgcn_mfma_f32_16x16x32_bf16(aM, bH, acc[nt], 0, 0, 0);
                acc[nt] = __builtin_amdgcn_mfma_f32_16x16x32_bf16(aH, bL, acc[nt], 0, 0, 0);
                acc[nt] = __builtin_amdgcn_mfma_f32_16x16x32_bf16(aM, bM, acc[nt], 0, 0, 0);
                acc[nt] = __builtin_amdgcn_mfma_f32_16x16x32_bf16(aL, bH, acc[nt], 0, 0, 0);
            }
        }
        if (tile + 1 < NTILE) convW(buf ^ 1, wa, wb);
        __syncthreads();
        buf ^= 1;
    }

    if (kh == 0) {
#pragma unroll
        for (int nt = 0; nt < 4; ++nt)
#pragma unroll
            for (int r = 0; r < 4; ++r) {
                const int t = mt * 16 + (lane >> 4) * 4 + r;
                const int e = nt * 16 + (lane & 15);
                *reinterpret_cast<float*>(smem + t * LSTR + e * 4) = acc[nt][r];
            }
    }
    __syncthreads();
    if (kh == 1) {
#pragma unroll
        for (int nt = 0; nt < 4; ++nt)
#pragma unroll
            for (int r = 0; r < 4; ++r) {
                const int t = mt * 16 + (lane >> 4) * 4 + r;
                const int e = nt * 16 + (lane & 15);
                float* p = reinterpret_cast<float*>(smem + t * LSTR + e * 4);
                *p += acc[nt][r];
            }
    }
    __syncthreads();

    float* maxArr = reinterpret_cast<float*>(smem + 18432);
    float* invArr = reinterpret_cast<float*>(smem + 18688);
    float* psum   = reinterpret_cast<float*>(smem + 18944);

    if (tid < BM) {
        const char* lrow = smem + tid * LSTR;
        float4 L[16];
#pragma unroll
        for (int i = 0; i < 16; ++i)
            L[i] = *reinterpret_cast<const float4*>(lrow + i * 16);
        float mx = -INFINITY;
#pragma unroll
        for (int i = 0; i < 16; ++i)
            mx = fmaxf(mx, fmaxf(fmaxf(L[i].x, L[i].y), fmaxf(L[i].z, L[i].w)));
        float v0 = -INFINITY, v1 = -INFINITY;
        int   i0 = NEXP, i1 = NEXP;
        float s = 0.f;
#pragma unroll
        for (int i = 0; i < 16; ++i) {
            const float vv[4] = {L[i].x, L[i].y, L[i].z, L[i].w};
#pragma unroll
            for (int c = 0; c < 4; ++c) {
                const float v = vv[c];
                const int  gi = i * 4 + c;
                s += __expf(v - mx);
                if (v > v0) { v1 = v0; i1 = i0; v0 = v; i0 = gi; }
                else if (v > v1) { v1 = v; i1 = gi; }
            }
        }
        maxArr[tid] = mx;
        invArr[tid] = 1.0f / s;
        const float q = __expf(v1 - v0);
        const float d = 1.0f + q;
        const size_t tok = (size_t)tok0 + tid;
        reinterpret_cast<float2*>(out)[tok]            = make_float2((float)i0, (float)i1);
        reinterpret_cast<float2*>(out + 2 * NTOK)[tok] = make_float2(1.0f / d, q / d);
    }
    __syncthreads();
    {
        const int e = tid & 63, grp = tid >> 6;
        float s = 0.f;
#pragma unroll
        for (int i = 0; i < 8; ++i) {
            const int t = grp * 8 + i;
            const float lg = *reinterpret_cast<const float*>(smem + t * LSTR + e * 4);
            s += __expf(lg - maxArr[t]) * invArr[t];
        }
        psum[grp * 64 + e] = s;
    }
    __syncthreads();
    if (tid < 64) {
        float s = 0.f;
#pragma unroll
        for (int g = 0; g < 8; ++g) s += psum[g * 64 + tid];
        atomicAdd(&expert_sums[tid], s);
    }
}

__global__ void loss_kernel(const float* __restrict__ sums, float* __restrict__ out)
{
    const int lane = threadIdx.x;  // 64 threads
    float pv = sums[lane] * (1.0f / (float)NTOK);  // avg_probs[lane]
    float m = pv;
#pragma unroll
    for (int off = 32; off; off >>= 1) m += __shfl_xor(m, off, 64);
    m *= (1.0f / (float)NEXP);
    float d = pv - m;
    float v = d * d;
#pragma unroll
    for (int off = 32; off; off >>= 1) v += __shfl_xor(v, off, 64);
    v *= (1.0f / (float)(NEXP - 1));  // ddof=1
    if (lane == 0) {
        float stdv = sqrtf(v);
        float r = stdv / (m + 1e-6f);
        out[4 * NTOK] = r * r;
    }
}

extern "C" void kernel_launch(void* const* d_in, const int* in_sizes, int n_in,
                              void* d_out, int out_size, void* d_ws, size_t ws_size,
                              hipStream_t stream)
{
    const float* x = (const float*)d_in[0];
    const float* W = (const float*)d_in[1];
    float* out  = (float*)d_out;
    float* sums = (float*)d_ws;

    hipMemsetAsync(d_ws, 0, 256, stream);

    if (ws_size >= WSPLIT_OFF + WSPLIT_BYTES) {
        char* wsAll = (char*)d_ws + WSPLIT_OFF;
        hipLaunchKernelGGL(wsplit_kernel, dim3(32), dim3(256), 0, stream, W, wsAll);
        hipLaunchKernelGGL(router_kernel, dim3(NTOK / BM), dim3(512), 0, stream,
                           x, wsAll, out, sums);
    } else {
        hipLaunchKernelGGL(router_fallback, dim3(NTOK / BM), dim3(512), 0, stream,
                           x, W, out, sums);
    }
    hipLaunchKernelGGL(loss_kernel, dim3(1), dim3(64), 0, stream, sums, out);
}